// Round 1
// baseline (1017.115 us; speedup 1.0000x reference)
//
#include <hip/hip_runtime.h>

typedef _Float16 half_t;
typedef __attribute__((ext_vector_type(8))) _Float16 half8;
typedef __attribute__((ext_vector_type(4))) _Float16 half4;
typedef __attribute__((ext_vector_type(4))) float f32x4;

#define MFMA16(a, b, c) __builtin_amdgcn_mfma_f32_16x16x32_f16((a), (b), (c), 0, 0, 0)

// ---------------- fp32 -> f16 convert (exact grids, no bounds check) ----------------
__global__ void cvt_f16(const float* __restrict__ src, half_t* __restrict__ dst) {
  int i = (blockIdx.x * 256 + threadIdx.x) * 4;
  float4 v = *(const float4*)(src + i);
  half4 o = { (half_t)v.x, (half_t)v.y, (half_t)v.z, (half_t)v.w };
  *(half4*)(dst + i) = o;
}

// ---------------- fused QKV projection: Y = X @ W^T + b, scatter to [bh][n][96] ----------------
// X [8192][1152] f16, W [1152][1152] f16 ([out][in] row-major = perfect B^T operand)
__global__ __launch_bounds__(256, 2) void gemm_qkv(
    const half_t* __restrict__ X,
    const half_t* __restrict__ Wq, const half_t* __restrict__ Wk, const half_t* __restrict__ Wv,
    const float* __restrict__ bq, const float* __restrict__ bk, const float* __restrict__ bv,
    half_t* __restrict__ qo, half_t* __restrict__ ko, half_t* __restrict__ vo)
{
  __shared__ half_t As[128 * 40];  // stride 40: b128 frag reads 16B-aligned, <=2-way banks
  __shared__ half_t Bs[128 * 40];
  const int t = threadIdx.x;
  const int w = t >> 6, L = t & 63, quad = L >> 4, c16 = L & 15;
  const int m0 = blockIdx.x * 128;
  const int by = blockIdx.y;
  const int mat = by / 9;                 // 0=q 1=k 2=v
  const int f0 = (by - mat * 9) * 128;    // feature tile base within [0,1152)
  const half_t* W = (mat == 0) ? Wq : (mat == 1) ? Wk : Wv;
  const int mB = (w & 1) * 64, nB = (w >> 1) * 64;
  f32x4 acc[4][4] = {};
  for (int k0 = 0; k0 < 1152; k0 += 32) {
    __syncthreads();
    #pragma unroll
    for (int i = 0; i < 2; ++i) {
      int c = t + i * 256;                 // 512 chunks of 8 halves per tile
      int row = c >> 2, cc = (c & 3) * 8;
      *(half8*)&As[row * 40 + cc] = *(const half8*)&X[(m0 + row) * 1152 + k0 + cc];
      *(half8*)&Bs[row * 40 + cc] = *(const half8*)&W[(f0 + row) * 1152 + k0 + cc];
    }
    __syncthreads();
    half8 a[4], b[4];
    #pragma unroll
    for (int i = 0; i < 4; ++i) {
      a[i] = *(const half8*)&As[(mB + i * 16 + c16) * 40 + quad * 8];
      b[i] = *(const half8*)&Bs[(nB + i * 16 + c16) * 40 + quad * 8];
    }
    #pragma unroll
    for (int mt = 0; mt < 4; ++mt)
      #pragma unroll
      for (int nt = 0; nt < 4; ++nt)
        acc[mt][nt] = MFMA16(a[mt], b[nt], acc[mt][nt]);
  }
  const float* bias = (mat == 0) ? bq : (mat == 1) ? bk : bv;
  half_t* dst = (mat == 0) ? qo : (mat == 1) ? ko : vo;
  const float scl = (mat == 0) ? 0.11785113f : 1.0f;  // 72^-0.5 folded into Q
  #pragma unroll
  for (int mt = 0; mt < 4; ++mt)
    #pragma unroll
    for (int nt = 0; nt < 4; ++nt) {
      int col = nB + nt * 16 + c16;
      int f = f0 + col;
      int h = f / 72, d = f - h * 72;
      float bb = bias[f];
      #pragma unroll
      for (int r = 0; r < 4; ++r) {
        int tok = m0 + mB + mt * 16 + quad * 4 + r;
        int b_ = tok >> 10, n = tok & 1023;
        dst[(((b_ * 16 + h) * 1024 + n) * 96) + d] = (half_t)((acc[mt][nt][r] + bb) * scl);
      }
    }
}

// ---------------- V [bh][n][96] -> Vt [bh][80][1024] (d>=72 rows stay memset-zero) ------------
__global__ void transpose_v(const half_t* __restrict__ v, half_t* __restrict__ vt) {
  __shared__ half_t tile[64][73];
  const int t = threadIdx.x;
  const int bh = blockIdx.y;
  const int n0 = blockIdx.x * 64;
  #pragma unroll
  for (int i = 0; i < 18; ++i) {          // 64*72 = 4608 = 18*256
    int flat = i * 256 + t;
    int n = flat / 72, d = flat - n * 72;
    tile[n][d] = v[(bh * 1024 + n0 + n) * 96 + d];
  }
  __syncthreads();
  #pragma unroll
  for (int i = 0; i < 18; ++i) {          // 72*64 = 4608
    int flat = i * 256 + t;
    int d = flat >> 6, n = flat & 63;
    vt[(bh * 80 + d) * 1024 + n0 + n] = tile[n][d];
  }
}

// ---------------- attention: two-pass (sum of exp, then normalize+write probs+PV) -------------
__global__ __launch_bounds__(256, 2) void attn(
    const half_t* __restrict__ q_ws,   // [bh][1024][96], SCALE folded, pads zero
    const half_t* __restrict__ k_ws,   // [bh][1024][96], pads zero
    const half_t* __restrict__ vt_ws,  // [bh][80][1024], rows 72..79 zero
    float* __restrict__ probs,         // [bh][1024][1024]
    half_t* __restrict__ ctx)          // [b][n][1152]
{
  __shared__ half_t Ks[32 * 104];      // 32 keys x 96 dims, stride 104
  __shared__ half_t Vts[80 * 40];      // 80 dims x 32 keys, stride 40
  __shared__ half_t Ps[4][32 * 40];    // per-wave p tile, 32q x 32k, stride 40
  const int t = threadIdx.x;
  const int w = t >> 6, L = t & 63, quad = L >> 4, c16 = L & 15;
  const int bh = blockIdx.y;
  const int qb = blockIdx.x * 128 + w * 32;   // wave's 32 queries
  const half_t* qp = q_ws + (bh * 1024 + qb) * 96;
  const half_t* kbase = k_ws + bh * 1024 * 96;
  const half_t* vtb = vt_ws + bh * 80 * 1024;

  half8 qf[2][3];
  #pragma unroll
  for (int mt = 0; mt < 2; ++mt)
    #pragma unroll
    for (int ks = 0; ks < 3; ++ks)
      qf[mt][ks] = *(const half8*)&qp[(mt * 16 + c16) * 96 + ks * 32 + quad * 8];

  // ---- pass 1: row sums of exp(s) ----
  float rsum[2][4] = {};
  for (int kt = 0; kt < 32; ++kt) {
    __syncthreads();
    for (int c = t; c < 384; c += 256) {       // 32 rows x 12 chunks
      int row = c / 12, cc = (c - row * 12) * 8;
      *(half8*)&Ks[row * 104 + cc] = *(const half8*)&kbase[(kt * 32 + row) * 96 + cc];
    }
    __syncthreads();
    #pragma unroll
    for (int nt = 0; nt < 2; ++nt) {
      half8 bf[3];
      #pragma unroll
      for (int ks = 0; ks < 3; ++ks)
        bf[ks] = *(const half8*)&Ks[(nt * 16 + c16) * 104 + ks * 32 + quad * 8];
      #pragma unroll
      for (int mt = 0; mt < 2; ++mt) {
        f32x4 s = {};
        #pragma unroll
        for (int ks = 0; ks < 3; ++ks) s = MFMA16(qf[mt][ks], bf[ks], s);
        #pragma unroll
        for (int r = 0; r < 4; ++r) rsum[mt][r] += __expf(s[r]);
      }
    }
  }
  float inv[2][4];
  #pragma unroll
  for (int mt = 0; mt < 2; ++mt)
    #pragma unroll
    for (int r = 0; r < 4; ++r) {
      float s = rsum[mt][r];
      s += __shfl_xor(s, 1); s += __shfl_xor(s, 2);
      s += __shfl_xor(s, 4); s += __shfl_xor(s, 8);   // stays inside the quad's 16 lanes
      inv[mt][r] = 1.0f / s;
    }

  // ---- pass 2: recompute S, write probs, accumulate O = P @ V ----
  f32x4 oacc[2][5] = {};
  float* pb = probs + ((long)bh * 1024 + qb) * 1024;
  for (int kt = 0; kt < 32; ++kt) {
    __syncthreads();
    for (int c = t; c < 384; c += 256) {
      int row = c / 12, cc = (c - row * 12) * 8;
      *(half8*)&Ks[row * 104 + cc] = *(const half8*)&kbase[(kt * 32 + row) * 96 + cc];
    }
    for (int c = t; c < 320; c += 256) {       // 80 rows x 4 chunks
      int row = c >> 2, cc = (c & 3) * 8;
      *(half8*)&Vts[row * 40 + cc] = *(const half8*)&vtb[row * 1024 + kt * 32 + cc];
    }
    __syncthreads();
    #pragma unroll
    for (int nt = 0; nt < 2; ++nt) {
      half8 bf[3];
      #pragma unroll
      for (int ks = 0; ks < 3; ++ks)
        bf[ks] = *(const half8*)&Ks[(nt * 16 + c16) * 104 + ks * 32 + quad * 8];
      #pragma unroll
      for (int mt = 0; mt < 2; ++mt) {
        f32x4 s = {};
        #pragma unroll
        for (int ks = 0; ks < 3; ++ks) s = MFMA16(qf[mt][ks], bf[ks], s);
        #pragma unroll
        for (int r = 0; r < 4; ++r) {
          float p = __expf(s[r]) * inv[mt][r];
          pb[(mt * 16 + quad * 4 + r) * 1024 + kt * 32 + nt * 16 + c16] = p;
          Ps[w][(mt * 16 + quad * 4 + r) * 40 + nt * 16 + c16] = (half_t)p;
        }
      }
    }
    __asm__ volatile("s_waitcnt lgkmcnt(0)" ::: "memory");  // wave-local P visibility
    #pragma unroll
    for (int mt = 0; mt < 2; ++mt) {
      half8 af = *(const half8*)&Ps[w][(mt * 16 + c16) * 40 + quad * 8];
      #pragma unroll
      for (int dt = 0; dt < 5; ++dt) {
        half8 bv = *(const half8*)&Vts[(dt * 16 + c16) * 40 + quad * 8];
        oacc[mt][dt] = MFMA16(af, bv, oacc[mt][dt]);
      }
    }
  }
  const int b_ = bh >> 4, h = bh & 15;
  #pragma unroll
  for (int mt = 0; mt < 2; ++mt)
    #pragma unroll
    for (int dt = 0; dt < 5; ++dt) {
      int d = dt * 16 + c16;
      if (d < 72) {
        #pragma unroll
        for (int r = 0; r < 4; ++r) {
          int q = qb + mt * 16 + quad * 4 + r;
          ctx[((b_ * 1024 + q) * 1152) + h * 72 + d] = (half_t)(oacc[mt][dt][r]);
        }
      }
    }
}

// ---------------- output projection: out = ctx @ o_w^T + o_b (fp32 out) ----------------
__global__ __launch_bounds__(256, 2) void gemm_o(
    const half_t* __restrict__ A, const half_t* __restrict__ W,
    const float* __restrict__ bias, float* __restrict__ out)
{
  __shared__ half_t As[128 * 40];
  __shared__ half_t Bs[128 * 40];
  const int t = threadIdx.x;
  const int w = t >> 6, L = t & 63, quad = L >> 4, c16 = L & 15;
  const int m0 = blockIdx.x * 128;
  const int f0 = blockIdx.y * 128;
  const int mB = (w & 1) * 64, nB = (w >> 1) * 64;
  f32x4 acc[4][4] = {};
  for (int k0 = 0; k0 < 1152; k0 += 32) {
    __syncthreads();
    #pragma unroll
    for (int i = 0; i < 2; ++i) {
      int c = t + i * 256;
      int row = c >> 2, cc = (c & 3) * 8;
      *(half8*)&As[row * 40 + cc] = *(const half8*)&A[(m0 + row) * 1152 + k0 + cc];
      *(half8*)&Bs[row * 40 + cc] = *(const half8*)&W[(f0 + row) * 1152 + k0 + cc];
    }
    __syncthreads();
    half8 a[4], b[4];
    #pragma unroll
    for (int i = 0; i < 4; ++i) {
      a[i] = *(const half8*)&As[(mB + i * 16 + c16) * 40 + quad * 8];
      b[i] = *(const half8*)&Bs[(nB + i * 16 + c16) * 40 + quad * 8];
    }
    #pragma unroll
    for (int mt = 0; mt < 4; ++mt)
      #pragma unroll
      for (int nt = 0; nt < 4; ++nt)
        acc[mt][nt] = MFMA16(a[mt], b[nt], acc[mt][nt]);
  }
  #pragma unroll
  for (int mt = 0; mt < 4; ++mt)
    #pragma unroll
    for (int nt = 0; nt < 4; ++nt) {
      int col = f0 + nB + nt * 16 + c16;
      float bb = bias[col];
      #pragma unroll
      for (int r = 0; r < 4; ++r) {
        int tok = m0 + mB + mt * 16 + quad * 4 + r;
        out[tok * 1152 + col] = acc[mt][nt][r] + bb;
      }
    }
}

extern "C" void kernel_launch(void* const* d_in, const int* in_sizes, int n_in,
                              void* d_out, int out_size, void* d_ws, size_t ws_size,
                              hipStream_t stream) {
  (void)in_sizes; (void)n_in; (void)out_size; (void)ws_size;
  const float* hidden = (const float*)d_in[0];
  const float* qw = (const float*)d_in[1];
  const float* qb = (const float*)d_in[2];
  const float* kw = (const float*)d_in[3];
  const float* kb = (const float*)d_in[4];
  const float* vw = (const float*)d_in[5];
  const float* vb = (const float*)d_in[6];
  const float* ow = (const float*)d_in[7];
  const float* ob = (const float*)d_in[8];
  float* out = (float*)d_out;                 // [8,1024,1152]
  float* probs = out + 9437184;               // [8,16,1024,1024]

  half_t* ws  = (half_t*)d_ws;
  half_t* Xh  = ws;                           //  9437184
  half_t* Wqh = Xh  + 9437184;                //  1327104
  half_t* Wkh = Wqh + 1327104;
  half_t* Wvh = Wkh + 1327104;
  half_t* Woh = Wvh + 1327104;
  half_t* Qw  = Woh + 1327104;                // 12582912  [bh][1024][96]
  half_t* Kw  = Qw  + 12582912;               // 12582912
  half_t* Vw  = Kw  + 12582912;               // 12582912
  half_t* Vt  = Vw  + 12582912;               // 10485760  [bh][80][1024]
  half_t* Ctx = Vt  + 10485760;               //  9437184  [8192][1152]

  // zero the padded regions (Q/K dim-pads must be exact zeros; Vt rows 72..79 zero)
  hipMemsetAsync(Qw, 0, (size_t)12582912 * 2, stream);
  hipMemsetAsync(Kw, 0, (size_t)12582912 * 2, stream);
  hipMemsetAsync(Vt, 0, (size_t)10485760 * 2, stream);

  cvt_f16<<<9216, 256, 0, stream>>>(hidden, Xh);   // 9437184/4/256
  cvt_f16<<<1296, 256, 0, stream>>>(qw, Wqh);      // 1327104/4/256
  cvt_f16<<<1296, 256, 0, stream>>>(kw, Wkh);
  cvt_f16<<<1296, 256, 0, stream>>>(vw, Wvh);
  cvt_f16<<<1296, 256, 0, stream>>>(ow, Woh);

  gemm_qkv<<<dim3(64, 27), 256, 0, stream>>>(Xh, Wqh, Wkh, Wvh, qb, kb, vb, Qw, Kw, Vw);
  transpose_v<<<dim3(16, 128), 256, 0, stream>>>(Vw, Vt);
  attn<<<dim3(8, 128), 256, 0, stream>>>(Qw, Kw, Vt, probs, Ctx);
  gemm_o<<<dim3(64, 9), 256, 0, stream>>>(Ctx, Woh, ob, out);
}

// Round 2
// 970.318 us; speedup vs baseline: 1.0482x; 1.0482x over previous
//
#include <hip/hip_runtime.h>

typedef _Float16 half_t;
typedef __attribute__((ext_vector_type(8))) _Float16 half8;
typedef __attribute__((ext_vector_type(4))) _Float16 half4;
typedef __attribute__((ext_vector_type(4))) float f32x4;

#define MFMA16(a, b, c) __builtin_amdgcn_mfma_f32_16x16x32_f16((a), (b), (c), 0, 0, 0)

// async global->LDS, 16B per lane; lds base must be wave-uniform (HW writes base + lane*16)
__device__ __forceinline__ void gld_lds16(const void* g, void* l) {
  __builtin_amdgcn_global_load_lds((const __attribute__((address_space(1))) void*)g,
                                   (__attribute__((address_space(3))) void*)l, 16, 0, 0);
}

// ---------------- fp32 -> f16 convert (exact grids, no bounds check) ----------------
__global__ void cvt_f16(const float* __restrict__ src, half_t* __restrict__ dst) {
  int i = (blockIdx.x * 256 + threadIdx.x) * 4;
  float4 v = *(const float4*)(src + i);
  half4 o = { (half_t)v.x, (half_t)v.y, (half_t)v.z, (half_t)v.w };
  *(half4*)(dst + i) = o;
}

// ---------------- fused QKV projection: Y = X @ W^T + b, scatter to [bh][n][96] ----------------
// X [8192][1152] f16, W [1152][1152] f16. Staging via global_load_lds into UNPADDED
// [128][32]-half tiles (64B rows; frag reads are 2-way bank-aliased = free, m97-proven).
__global__ __launch_bounds__(256, 2) void gemm_qkv(
    const half_t* __restrict__ X,
    const half_t* __restrict__ Wq, const half_t* __restrict__ Wk, const half_t* __restrict__ Wv,
    const float* __restrict__ bq, const float* __restrict__ bk, const float* __restrict__ bv,
    half_t* __restrict__ qo, half_t* __restrict__ ko, half_t* __restrict__ vo)
{
  __shared__ __align__(16) half_t As[128 * 32];
  __shared__ __align__(16) half_t Bs[128 * 32];
  const int t = threadIdx.x;
  const int w = t >> 6, L = t & 63, quad = L >> 4, c16 = L & 15;
  const int m0 = blockIdx.x * 128;
  const int by = blockIdx.y;
  const int mat = by / 9;                 // 0=q 1=k 2=v
  const int f0 = (by - mat * 9) * 128;
  const half_t* W = (mat == 0) ? Wq : (mat == 1) ? Wk : Wv;
  const int mB = (w & 1) * 64, nB = (w >> 1) * 64;
  f32x4 acc[4][4] = {};
  for (int k0 = 0; k0 < 1152; k0 += 32) {
    __syncthreads();
    #pragma unroll
    for (int i = 0; i < 2; ++i) {
      int f = w * 2048 + i * 1024 + L * 16;           // byte offset within tile
      int row = f >> 6, colb = f & 63;
      gld_lds16((const char*)&X[(m0 + row) * 1152 + k0] + colb,
                (char*)As + w * 2048 + i * 1024);
      gld_lds16((const char*)&W[(f0 + row) * 1152 + k0] + colb,
                (char*)Bs + w * 2048 + i * 1024);
    }
    __syncthreads();
    half8 a[4], b[4];
    #pragma unroll
    for (int i = 0; i < 4; ++i) {
      a[i] = *(const half8*)&As[(mB + i * 16 + c16) * 32 + quad * 8];
      b[i] = *(const half8*)&Bs[(nB + i * 16 + c16) * 32 + quad * 8];
    }
    #pragma unroll
    for (int mt = 0; mt < 4; ++mt)
      #pragma unroll
      for (int nt = 0; nt < 4; ++nt)
        acc[mt][nt] = MFMA16(a[mt], b[nt], acc[mt][nt]);
  }
  const float* bias = (mat == 0) ? bq : (mat == 1) ? bk : bv;
  half_t* dst = (mat == 0) ? qo : (mat == 1) ? ko : vo;
  // Q scale = 72^-0.5 * log2(e): softmax later uses raw exp2 (v_exp_f32, no per-elem mul)
  const float scl = (mat == 0) ? 0.17002322f : 1.0f;
  #pragma unroll
  for (int mt = 0; mt < 4; ++mt)
    #pragma unroll
    for (int nt = 0; nt < 4; ++nt) {
      int col = nB + nt * 16 + c16;
      int f = f0 + col;
      int h = f / 72, d = f - h * 72;
      float bb = bias[f];
      #pragma unroll
      for (int r = 0; r < 4; ++r) {
        int tok = m0 + mB + mt * 16 + quad * 4 + r;
        int b_ = tok >> 10, n = tok & 1023;
        dst[(((b_ * 16 + h) * 1024 + n) * 96) + d] = (half_t)((acc[mt][nt][r] + bb) * scl);
      }
    }
}

// ---------------- V [bh][n][96] -> Vt [bh][80][1024] (d>=72 rows stay memset-zero) ------------
__global__ void transpose_v(const half_t* __restrict__ v, half_t* __restrict__ vt) {
  __shared__ half_t tile[64][73];
  const int t = threadIdx.x;
  const int bh = blockIdx.y;
  const int n0 = blockIdx.x * 64;
  #pragma unroll
  for (int i = 0; i < 18; ++i) {
    int flat = i * 256 + t;
    int n = flat / 72, d = flat - n * 72;
    tile[n][d] = v[(bh * 1024 + n0 + n) * 96 + d];
  }
  __syncthreads();
  #pragma unroll
  for (int i = 0; i < 18; ++i) {
    int flat = i * 256 + t;
    int d = flat >> 6, n = flat & 63;
    vt[(bh * 80 + d) * 1024 + n0 + n] = tile[n][d];
  }
}

// ---------------- attention: two-pass, 64 queries/wave, exp2 softmax -------------
__global__ __launch_bounds__(256, 2) void attn(
    const half_t* __restrict__ q_ws,   // [bh][1024][96], scale*log2e folded, pads zero
    const half_t* __restrict__ k_ws,   // [bh][1024][96], pads zero
    const half_t* __restrict__ vt_ws,  // [bh][80][1024], rows 72..79 zero
    float* __restrict__ probs,         // [bh][1024][1024]
    half_t* __restrict__ ctx)          // [b][n][1152]
{
  __shared__ half_t Ks[32 * 104];      // 32 keys x 96 dims, stride 104 (2-way alias)
  __shared__ half_t Vts[80 * 40];      // 80 dims x 32 keys
  __shared__ half_t Ps[4][64 * 40];    // per-wave p tile, 64q x 32k
  const int t = threadIdx.x;
  const int w = t >> 6, L = t & 63, quad = L >> 4, c16 = L & 15;
  const int bh = blockIdx.y;
  const int qb = blockIdx.x * 256 + w * 64;   // wave's 64 queries
  const half_t* qp = q_ws + (bh * 1024 + qb) * 96;
  const half_t* kbase = k_ws + bh * 1024 * 96;
  const half_t* vtb = vt_ws + bh * 80 * 1024;

  half8 qf[4][3];
  #pragma unroll
  for (int mt = 0; mt < 4; ++mt)
    #pragma unroll
    for (int ks = 0; ks < 3; ++ks)
      qf[mt][ks] = *(const half8*)&qp[(mt * 16 + c16) * 96 + ks * 32 + quad * 8];

  // ---- pass 1: row sums of exp2(s) ----
  float rsum[4][4] = {};
  for (int kt = 0; kt < 32; ++kt) {
    __syncthreads();
    for (int c = t; c < 384; c += 256) {
      int row = c / 12, cc = (c - row * 12) * 8;
      *(half8*)&Ks[row * 104 + cc] = *(const half8*)&kbase[(kt * 32 + row) * 96 + cc];
    }
    __syncthreads();
    #pragma unroll
    for (int nt = 0; nt < 2; ++nt) {
      half8 bf[3];
      #pragma unroll
      for (int ks = 0; ks < 3; ++ks)
        bf[ks] = *(const half8*)&Ks[(nt * 16 + c16) * 104 + ks * 32 + quad * 8];
      #pragma unroll
      for (int mt = 0; mt < 4; ++mt) {
        f32x4 s = {};
        #pragma unroll
        for (int ks = 0; ks < 3; ++ks) s = MFMA16(qf[mt][ks], bf[ks], s);
        #pragma unroll
        for (int r = 0; r < 4; ++r) rsum[mt][r] += __builtin_amdgcn_exp2f(s[r]);
      }
    }
  }
  float inv[4][4];
  #pragma unroll
  for (int mt = 0; mt < 4; ++mt)
    #pragma unroll
    for (int r = 0; r < 4; ++r) {
      float s = rsum[mt][r];
      s += __shfl_xor(s, 1); s += __shfl_xor(s, 2);
      s += __shfl_xor(s, 4); s += __shfl_xor(s, 8);
      inv[mt][r] = 1.0f / s;
    }

  // ---- pass 2: recompute S, write probs, accumulate O = P @ V ----
  f32x4 oacc[4][5] = {};
  float* pb = probs + ((long)bh * 1024 + qb) * 1024;
  for (int kt = 0; kt < 32; ++kt) {
    __syncthreads();
    for (int c = t; c < 384; c += 256) {
      int row = c / 12, cc = (c - row * 12) * 8;
      *(half8*)&Ks[row * 104 + cc] = *(const half8*)&kbase[(kt * 32 + row) * 96 + cc];
    }
    for (int c = t; c < 320; c += 256) {
      int row = c >> 2, cc = (c & 3) * 8;
      *(half8*)&Vts[row * 40 + cc] = *(const half8*)&vtb[row * 1024 + kt * 32 + cc];
    }
    __syncthreads();
    #pragma unroll
    for (int nt = 0; nt < 2; ++nt) {
      half8 bf[3];
      #pragma unroll
      for (int ks = 0; ks < 3; ++ks)
        bf[ks] = *(const half8*)&Ks[(nt * 16 + c16) * 104 + ks * 32 + quad * 8];
      #pragma unroll
      for (int mt = 0; mt < 4; ++mt) {
        f32x4 s = {};
        #pragma unroll
        for (int ks = 0; ks < 3; ++ks) s = MFMA16(qf[mt][ks], bf[ks], s);
        #pragma unroll
        for (int r = 0; r < 4; ++r) {
          float p = __builtin_amdgcn_exp2f(s[r]) * inv[mt][r];
          pb[(mt * 16 + quad * 4 + r) * 1024 + kt * 32 + nt * 16 + c16] = p;
          Ps[w][(mt * 16 + quad * 4 + r) * 40 + nt * 16 + c16] = (half_t)p;
        }
      }
    }
    __asm__ volatile("s_waitcnt lgkmcnt(0)" ::: "memory");  // wave-local P visibility
    half8 bv[5];
    #pragma unroll
    for (int dt = 0; dt < 5; ++dt)
      bv[dt] = *(const half8*)&Vts[(dt * 16 + c16) * 40 + quad * 8];
    #pragma unroll
    for (int mt = 0; mt < 4; ++mt) {
      half8 af = *(const half8*)&Ps[w][(mt * 16 + c16) * 40 + quad * 8];
      #pragma unroll
      for (int dt = 0; dt < 5; ++dt)
        oacc[mt][dt] = MFMA16(af, bv[dt], oacc[mt][dt]);
    }
  }
  const int b_ = bh >> 4, h = bh & 15;
  #pragma unroll
  for (int mt = 0; mt < 4; ++mt)
    #pragma unroll
    for (int dt = 0; dt < 5; ++dt) {
      int d = dt * 16 + c16;
      if (d < 72) {
        #pragma unroll
        for (int r = 0; r < 4; ++r) {
          int q = qb + mt * 16 + quad * 4 + r;
          ctx[((b_ * 1024 + q) * 1152) + h * 72 + d] = (half_t)(oacc[mt][dt][r]);
        }
      }
    }
}

// ---------------- output projection: out = ctx @ o_w^T + o_b (fp32 out) ----------------
__global__ __launch_bounds__(256, 2) void gemm_o(
    const half_t* __restrict__ A, const half_t* __restrict__ W,
    const float* __restrict__ bias, float* __restrict__ out)
{
  __shared__ __align__(16) half_t As[128 * 32];
  __shared__ __align__(16) half_t Bs[128 * 32];
  const int t = threadIdx.x;
  const int w = t >> 6, L = t & 63, quad = L >> 4, c16 = L & 15;
  const int m0 = blockIdx.x * 128;
  const int f0 = blockIdx.y * 128;
  const int mB = (w & 1) * 64, nB = (w >> 1) * 64;
  f32x4 acc[4][4] = {};
  for (int k0 = 0; k0 < 1152; k0 += 32) {
    __syncthreads();
    #pragma unroll
    for (int i = 0; i < 2; ++i) {
      int f = w * 2048 + i * 1024 + L * 16;
      int row = f >> 6, colb = f & 63;
      gld_lds16((const char*)&A[(m0 + row) * 1152 + k0] + colb,
                (char*)As + w * 2048 + i * 1024);
      gld_lds16((const char*)&W[(f0 + row) * 1152 + k0] + colb,
                (char*)Bs + w * 2048 + i * 1024);
    }
    __syncthreads();
    half8 a[4], b[4];
    #pragma unroll
    for (int i = 0; i < 4; ++i) {
      a[i] = *(const half8*)&As[(mB + i * 16 + c16) * 32 + quad * 8];
      b[i] = *(const half8*)&Bs[(nB + i * 16 + c16) * 32 + quad * 8];
    }
    #pragma unroll
    for (int mt = 0; mt < 4; ++mt)
      #pragma unroll
      for (int nt = 0; nt < 4; ++nt)
        acc[mt][nt] = MFMA16(a[mt], b[nt], acc[mt][nt]);
  }
  #pragma unroll
  for (int mt = 0; mt < 4; ++mt)
    #pragma unroll
    for (int nt = 0; nt < 4; ++nt) {
      int col = f0 + nB + nt * 16 + c16;
      float bb = bias[col];
      #pragma unroll
      for (int r = 0; r < 4; ++r) {
        int tok = m0 + mB + mt * 16 + quad * 4 + r;
        out[tok * 1152 + col] = acc[mt][nt][r] + bb;
      }
    }
}

extern "C" void kernel_launch(void* const* d_in, const int* in_sizes, int n_in,
                              void* d_out, int out_size, void* d_ws, size_t ws_size,
                              hipStream_t stream) {
  (void)in_sizes; (void)n_in; (void)out_size; (void)ws_size;
  const float* hidden = (const float*)d_in[0];
  const float* qw = (const float*)d_in[1];
  const float* qb = (const float*)d_in[2];
  const float* kw = (const float*)d_in[3];
  const float* kb = (const float*)d_in[4];
  const float* vw = (const float*)d_in[5];
  const float* vb = (const float*)d_in[6];
  const float* ow = (const float*)d_in[7];
  const float* ob = (const float*)d_in[8];
  float* out = (float*)d_out;                 // [8,1024,1152]
  float* probs = out + 9437184;               // [8,16,1024,1024]

  half_t* ws  = (half_t*)d_ws;
  half_t* Xh  = ws;                           //  9437184
  half_t* Wqh = Xh  + 9437184;                //  1327104
  half_t* Wkh = Wqh + 1327104;
  half_t* Wvh = Wkh + 1327104;
  half_t* Woh = Wvh + 1327104;
  half_t* Qw  = Woh + 1327104;                // 12582912  [bh][1024][96]
  half_t* Kw  = Qw  + 12582912;               // 12582912
  half_t* Vw  = Kw  + 12582912;               // 12582912
  half_t* Vt  = Vw  + 12582912;               // 10485760  [bh][80][1024]
  half_t* Ctx = Vt  + 10485760;               //  9437184  [8192][1152]

  hipMemsetAsync(Qw, 0, (size_t)12582912 * 2, stream);
  hipMemsetAsync(Kw, 0, (size_t)12582912 * 2, stream);
  hipMemsetAsync(Vt, 0, (size_t)10485760 * 2, stream);

  cvt_f16<<<9216, 256, 0, stream>>>(hidden, Xh);
  cvt_f16<<<1296, 256, 0, stream>>>(qw, Wqh);
  cvt_f16<<<1296, 256, 0, stream>>>(kw, Wkh);
  cvt_f16<<<1296, 256, 0, stream>>>(vw, Wvh);
  cvt_f16<<<1296, 256, 0, stream>>>(ow, Woh);

  gemm_qkv<<<dim3(64, 27), 256, 0, stream>>>(Xh, Wqh, Wkh, Wvh, qb, kb, vb, Qw, Kw, Vw);
  transpose_v<<<dim3(16, 128), 256, 0, stream>>>(Vw, Vt);
  attn<<<dim3(4, 128), 256, 0, stream>>>(Qw, Kw, Vt, probs, Ctx);
  gemm_o<<<dim3(64, 9), 256, 0, stream>>>(Ctx, Woh, ob, out);
}